// Round 1
// baseline (175.705 us; speedup 1.0000x reference)
//
#include <hip/hip_runtime.h>

#define BB 1024
#define SS 192
#define DD 512
#define NUM_LAYERS 3
#define LN_EPS 1e-5f

// Precompute start[b] = first index with mask>0 (argmax semantics: 0 if none).
__global__ void start_kernel(const int* __restrict__ mask, int* __restrict__ start) {
    int b = blockIdx.x * blockDim.x + threadIdx.x;
    if (b >= BB) return;
    const int* m = mask + b * SS;
    int st = 0;
    // scan backward keeping the earliest set index; defaults to 0 like argmax
    for (int i = SS - 1; i >= 0; --i) {
        if (m[i] > 0) st = i;
    }
    start[b] = st;
}

// One block per (b, s) row. 128 threads x float4 = 512 elements.
__global__ __launch_bounds__(128) void fused_kernel(
    const float* __restrict__ tok,
    const int* __restrict__ mask,
    const float* __restrict__ item_pos,
    const float* __restrict__ layer_emb,
    const float* __restrict__ decay,
    const float* __restrict__ lnw,
    const float* __restrict__ lnb,
    const int* __restrict__ start,
    float* __restrict__ out)
{
    const int row = blockIdx.x;          // b*S + s
    const int b = row / SS;
    const int s = row - b * SS;
    const int t = threadIdx.x;           // 0..127

    float* o = out + (size_t)row * DD;

    const int mk = mask[row];
    if (mk == 0) {
        // padded position: output is exactly zero (normed * 0)
        float4 z = make_float4(0.f, 0.f, 0.f, 0.f);
        reinterpret_cast<float4*>(o)[t] = z;
        return;
    }

    const int st = start[b];
    const int pos = s - st;                       // >= 0 for any kept position
    const int item_idx = pos / NUM_LAYERS;
    const int layer_idx = pos - item_idx * NUM_LAYERS;

    const float* x = tok + (size_t)row * DD;
    float4 xv = reinterpret_cast<const float4*>(x)[t];

    const float4 a1 = reinterpret_cast<const float4*>(item_pos + item_idx * DD)[t];
    const float4 a2 = reinterpret_cast<const float4*>(layer_emb + layer_idx * DD)[t];
    const float4 a3 = reinterpret_cast<const float4*>(decay + item_idx * DD)[t];

    xv.x += a1.x + a2.x + a3.x;
    xv.y += a1.y + a2.y + a3.y;
    xv.z += a1.z + a2.z + a3.z;
    xv.w += a1.w + a2.w + a3.w;

    // single-pass sum & sum-of-squares
    float sum = xv.x + xv.y + xv.z + xv.w;
    float sq  = xv.x * xv.x + xv.y * xv.y + xv.z * xv.z + xv.w * xv.w;

    // wave64 butterfly-free down-reduce
    #pragma unroll
    for (int off = 32; off > 0; off >>= 1) {
        sum += __shfl_down(sum, off, 64);
        sq  += __shfl_down(sq,  off, 64);
    }

    __shared__ float2 partial[2];
    const int wave = t >> 6;
    if ((t & 63) == 0) partial[wave] = make_float2(sum, sq);
    __syncthreads();

    const float tsum = partial[0].x + partial[1].x;
    const float tsq  = partial[0].y + partial[1].y;

    const float mu  = tsum * (1.0f / DD);
    const float var = tsq * (1.0f / DD) - mu * mu;
    const float inv = rsqrtf(var + LN_EPS);

    const float4 wv = reinterpret_cast<const float4*>(lnw)[t];
    const float4 bv = reinterpret_cast<const float4*>(lnb)[t];

    float4 ov;
    ov.x = (xv.x - mu) * inv * wv.x + bv.x;
    ov.y = (xv.y - mu) * inv * wv.y + bv.y;
    ov.z = (xv.z - mu) * inv * wv.z + bv.z;
    ov.w = (xv.w - mu) * inv * wv.w + bv.w;

    reinterpret_cast<float4*>(o)[t] = ov;
}

extern "C" void kernel_launch(void* const* d_in, const int* in_sizes, int n_in,
                              void* d_out, int out_size, void* d_ws, size_t ws_size,
                              hipStream_t stream) {
    const float* tok       = (const float*)d_in[0];   // (B,S,D)
    const int*   mask      = (const int*)d_in[1];     // (B,S)
    const float* item_pos  = (const float*)d_in[2];   // (64,D)
    const float* layer_emb = (const float*)d_in[3];   // (3,D)
    const float* decay     = (const float*)d_in[4];   // (64,D)
    const float* lnw       = (const float*)d_in[5];   // (D,)
    const float* lnb       = (const float*)d_in[6];   // (D,)
    float* out = (float*)d_out;

    int* start = (int*)d_ws;  // B ints

    start_kernel<<<(BB + 255) / 256, 256, 0, stream>>>(mask, start);
    fused_kernel<<<BB * SS, 128, 0, stream>>>(tok, mask, item_pos, layer_emb,
                                              decay, lnw, lnb, start, out);
}

// Round 2
// 157.871 us; speedup vs baseline: 1.1130x; 1.1130x over previous
//
#include <hip/hip_runtime.h>

#define BB 1024
#define SS 192
#define DD 512
#define NUM_LAYERS 3
#define LN_EPS 1e-5f

// One wave per batch row: ballot-based first-set-index (argmax semantics: 0 if none).
__global__ __launch_bounds__(256) void start_kernel(const int* __restrict__ mask,
                                                    int* __restrict__ start) {
    const int b = (blockIdx.x * blockDim.x + threadIdx.x) >> 6;
    const int lane = threadIdx.x & 63;
    if (b >= BB) return;
    const int* m = mask + b * SS;
    const unsigned long long b0 = __ballot(m[lane] > 0);
    const unsigned long long b1 = __ballot(m[lane + 64] > 0);
    const unsigned long long b2 = __ballot(m[lane + 128] > 0);
    int idx;
    if (b0)      idx = __ffsll(b0) - 1;
    else if (b1) idx = 64 + __ffsll(b1) - 1;
    else if (b2) idx = 128 + __ffsll(b2) - 1;
    else         idx = 0;
    if (lane == 0) start[b] = idx;
}

// One WAVE per (b,s) row; 256-thread block = 4 independent rows, no LDS/barrier.
// Each lane owns 2 x float4 (32B), fully coalesced.
__global__ __launch_bounds__(256) void fused_kernel(
    const float* __restrict__ tok,
    const int* __restrict__ mask,
    const float* __restrict__ item_pos,
    const float* __restrict__ layer_emb,
    const float* __restrict__ decay,
    const float* __restrict__ lnw,
    const float* __restrict__ lnb,
    const int* __restrict__ start,
    float* __restrict__ out)
{
    const int wid = threadIdx.x >> 6;                 // 0..3
    const int lane = threadIdx.x & 63;                // 0..63
    const int row = blockIdx.x * 4 + wid;             // b*S + s
    const int b = row / SS;
    const int s = row - b * SS;

    float4* o4 = reinterpret_cast<float4*>(out + (size_t)row * DD);

    if (mask[row] == 0) {
        const float4 z = make_float4(0.f, 0.f, 0.f, 0.f);
        o4[lane] = z;
        o4[lane + 64] = z;
        return;
    }

    const int st = start[b];
    const int pos = s - st;                           // >= 0 for kept positions
    const int item_idx = pos / NUM_LAYERS;
    const int layer_idx = pos - item_idx * NUM_LAYERS;

    const float4* x4 = reinterpret_cast<const float4*>(tok + (size_t)row * DD);
    float4 xv0 = x4[lane];
    float4 xv1 = x4[lane + 64];

    const float4* i4 = reinterpret_cast<const float4*>(item_pos + item_idx * DD);
    const float4* l4 = reinterpret_cast<const float4*>(layer_emb + layer_idx * DD);
    const float4* d4 = reinterpret_cast<const float4*>(decay + item_idx * DD);

    const float4 i0 = i4[lane], i1 = i4[lane + 64];
    const float4 l0 = l4[lane], l1 = l4[lane + 64];
    const float4 dd0 = d4[lane], dd1 = d4[lane + 64];

    xv0.x += i0.x + l0.x + dd0.x;  xv0.y += i0.y + l0.y + dd0.y;
    xv0.z += i0.z + l0.z + dd0.z;  xv0.w += i0.w + l0.w + dd0.w;
    xv1.x += i1.x + l1.x + dd1.x;  xv1.y += i1.y + l1.y + dd1.y;
    xv1.z += i1.z + l1.z + dd1.z;  xv1.w += i1.w + l1.w + dd1.w;

    float sum = xv0.x + xv0.y + xv0.z + xv0.w + xv1.x + xv1.y + xv1.z + xv1.w;
    float sq  = xv0.x * xv0.x + xv0.y * xv0.y + xv0.z * xv0.z + xv0.w * xv0.w
              + xv1.x * xv1.x + xv1.y * xv1.y + xv1.z * xv1.z + xv1.w * xv1.w;

    // butterfly reduce: all 64 lanes end with the row total
    #pragma unroll
    for (int m = 32; m > 0; m >>= 1) {
        sum += __shfl_xor(sum, m, 64);
        sq  += __shfl_xor(sq,  m, 64);
    }

    const float mu  = sum * (1.0f / DD);
    const float var = sq * (1.0f / DD) - mu * mu;
    const float inv = rsqrtf(var + LN_EPS);

    const float4* w4 = reinterpret_cast<const float4*>(lnw);
    const float4* bb4 = reinterpret_cast<const float4*>(lnb);
    const float4 w0 = w4[lane], w1 = w4[lane + 64];
    const float4 b0 = bb4[lane], b1 = bb4[lane + 64];

    float4 ov0, ov1;
    ov0.x = (xv0.x - mu) * inv * w0.x + b0.x;
    ov0.y = (xv0.y - mu) * inv * w0.y + b0.y;
    ov0.z = (xv0.z - mu) * inv * w0.z + b0.z;
    ov0.w = (xv0.w - mu) * inv * w0.w + b0.w;
    ov1.x = (xv1.x - mu) * inv * w1.x + b1.x;
    ov1.y = (xv1.y - mu) * inv * w1.y + b1.y;
    ov1.z = (xv1.z - mu) * inv * w1.z + b1.z;
    ov1.w = (xv1.w - mu) * inv * w1.w + b1.w;

    o4[lane] = ov0;
    o4[lane + 64] = ov1;
}

extern "C" void kernel_launch(void* const* d_in, const int* in_sizes, int n_in,
                              void* d_out, int out_size, void* d_ws, size_t ws_size,
                              hipStream_t stream) {
    const float* tok       = (const float*)d_in[0];   // (B,S,D)
    const int*   mask      = (const int*)d_in[1];     // (B,S)
    const float* item_pos  = (const float*)d_in[2];   // (64,D)
    const float* layer_emb = (const float*)d_in[3];   // (3,D)
    const float* decay     = (const float*)d_in[4];   // (64,D)
    const float* lnw       = (const float*)d_in[5];   // (D,)
    const float* lnb       = (const float*)d_in[6];   // (D,)
    float* out = (float*)d_out;

    int* start = (int*)d_ws;  // B ints

    start_kernel<<<(BB * 64 + 255) / 256, 256, 0, stream>>>(mask, start);
    fused_kernel<<<(BB * SS) / 4, 256, 0, stream>>>(tok, mask, item_pos, layer_emb,
                                                    decay, lnw, lnb, start, out);
}

// Round 3
// 147.142 us; speedup vs baseline: 1.1941x; 1.0729x over previous
//
#include <hip/hip_runtime.h>

#define BB 1024
#define SS 192
#define DD 512
#define NUM_LAYERS 3
#define LN_EPS 1e-5f
#define NROWS (BB * SS)
#define FUSED_BLOCKS 2048
#define NWAVES (FUSED_BLOCKS * 4)

// Merged prep:
//  blocks [0, SS)        : build add_tab[pos] = item_pos[pos/3] + layer[pos%3] + decay[pos/3]
//  blocks [SS, SS+256)   : start[b] via ballot (4 waves/block, 1 b per wave); start=SS if row empty
__global__ __launch_bounds__(256) void prep_kernel(
    const int* __restrict__ mask,
    const float* __restrict__ item_pos,
    const float* __restrict__ layer_emb,
    const float* __restrict__ decay,
    float* __restrict__ add_tab,
    int* __restrict__ start)
{
    if (blockIdx.x < SS) {
        const int p = blockIdx.x;                 // content-relative position 0..191
        const int t = threadIdx.x;
        if (t < DD / 4) {
            const int item = p / NUM_LAYERS;
            const int layer = p - item * NUM_LAYERS;
            const float4 iv = reinterpret_cast<const float4*>(item_pos + item * DD)[t];
            const float4 lv = reinterpret_cast<const float4*>(layer_emb + layer * DD)[t];
            const float4 dv = reinterpret_cast<const float4*>(decay + item * DD)[t];
            float4 v;
            v.x = iv.x + lv.x + dv.x;
            v.y = iv.y + lv.y + dv.y;
            v.z = iv.z + lv.z + dv.z;
            v.w = iv.w + lv.w + dv.w;
            reinterpret_cast<float4*>(add_tab + p * DD)[t] = v;
        }
    } else {
        const int b = (blockIdx.x - SS) * 4 + (threadIdx.x >> 6);
        const int lane = threadIdx.x & 63;
        if (b < BB) {
            const int* m = mask + b * SS;
            const unsigned long long b0 = __ballot(m[lane] > 0);
            const unsigned long long b1 = __ballot(m[lane + 64] > 0);
            const unsigned long long b2 = __ballot(m[lane + 128] > 0);
            int idx;
            if (b0)      idx = __ffsll(b0) - 1;
            else if (b1) idx = 64 + __ffsll(b1) - 1;
            else if (b2) idx = 128 + __ffsll(b2) - 1;
            else         idx = SS;               // no content: treat all as padded
            if (lane == 0) start[b] = idx;
        }
    }
}

// Persistent waves: one wave per row per iteration; lnw/lnb live in registers.
__global__ __launch_bounds__(256) void fused_kernel(
    const float* __restrict__ tok,
    const float* __restrict__ add_tab,
    const float* __restrict__ lnw,
    const float* __restrict__ lnb,
    const int* __restrict__ start,
    float* __restrict__ out)
{
    const int wid = threadIdx.x >> 6;
    const int lane = threadIdx.x & 63;
    const int l0 = lane;
    const int l1 = lane + 64;

    // loop-invariant: LN params (2KB each, fully coalesced once per wave)
    const float4 w0 = reinterpret_cast<const float4*>(lnw)[l0];
    const float4 w1 = reinterpret_cast<const float4*>(lnw)[l1];
    const float4 c0 = reinterpret_cast<const float4*>(lnb)[l0];
    const float4 c1 = reinterpret_cast<const float4*>(lnb)[l1];

    const int wave = blockIdx.x * 4 + wid;

    for (int row = wave; row < NROWS; row += NWAVES) {
        const int b = row / SS;
        const int s = row - b * SS;
        const int st = start[b];

        float4* o4 = reinterpret_cast<float4*>(out + (size_t)row * DD);

        if (s < st) {
            const float4 z = make_float4(0.f, 0.f, 0.f, 0.f);
            o4[l0] = z;
            o4[l1] = z;
            continue;
        }

        const int pos = s - st;                  // 0..191

        const float4* x4 = reinterpret_cast<const float4*>(tok + (size_t)row * DD);
        float4 xv0 = x4[l0];
        float4 xv1 = x4[l1];

        const float4* a4 = reinterpret_cast<const float4*>(add_tab + pos * DD);
        const float4 a0 = a4[l0];
        const float4 a1 = a4[l1];

        xv0.x += a0.x;  xv0.y += a0.y;  xv0.z += a0.z;  xv0.w += a0.w;
        xv1.x += a1.x;  xv1.y += a1.y;  xv1.z += a1.z;  xv1.w += a1.w;

        float sum = xv0.x + xv0.y + xv0.z + xv0.w + xv1.x + xv1.y + xv1.z + xv1.w;
        float sq  = xv0.x * xv0.x + xv0.y * xv0.y + xv0.z * xv0.z + xv0.w * xv0.w
                  + xv1.x * xv1.x + xv1.y * xv1.y + xv1.z * xv1.z + xv1.w * xv1.w;

        #pragma unroll
        for (int m = 32; m > 0; m >>= 1) {
            sum += __shfl_xor(sum, m, 64);
            sq  += __shfl_xor(sq,  m, 64);
        }

        const float mu  = sum * (1.0f / DD);
        const float var = sq * (1.0f / DD) - mu * mu;
        const float inv = rsqrtf(var + LN_EPS);

        float4 ov0, ov1;
        ov0.x = (xv0.x - mu) * inv * w0.x + c0.x;
        ov0.y = (xv0.y - mu) * inv * w0.y + c0.y;
        ov0.z = (xv0.z - mu) * inv * w0.z + c0.z;
        ov0.w = (xv0.w - mu) * inv * w0.w + c0.w;
        ov1.x = (xv1.x - mu) * inv * w1.x + c1.x;
        ov1.y = (xv1.y - mu) * inv * w1.y + c1.y;
        ov1.z = (xv1.z - mu) * inv * w1.z + c1.z;
        ov1.w = (xv1.w - mu) * inv * w1.w + c1.w;

        o4[l0] = ov0;
        o4[l1] = ov1;
    }
}

extern "C" void kernel_launch(void* const* d_in, const int* in_sizes, int n_in,
                              void* d_out, int out_size, void* d_ws, size_t ws_size,
                              hipStream_t stream) {
    const float* tok       = (const float*)d_in[0];   // (B,S,D)
    const int*   mask      = (const int*)d_in[1];     // (B,S)
    const float* item_pos  = (const float*)d_in[2];   // (64,D)
    const float* layer_emb = (const float*)d_in[3];   // (3,D)
    const float* decay     = (const float*)d_in[4];   // (64,D)
    const float* lnw       = (const float*)d_in[5];   // (D,)
    const float* lnb       = (const float*)d_in[6];   // (D,)
    float* out = (float*)d_out;

    // workspace layout: [ add_tab: SS*DD floats ][ start: BB ints ]
    float* add_tab = (float*)d_ws;
    int* start = (int*)((char*)d_ws + (size_t)SS * DD * sizeof(float));

    prep_kernel<<<SS + 256, 256, 0, stream>>>(mask, item_pos, layer_emb, decay,
                                              add_tab, start);
    fused_kernel<<<FUSED_BLOCKS, 256, 0, stream>>>(tok, add_tab, lnw, lnb, start, out);
}